// Round 13
// baseline (202.586 us; speedup 1.0000x reference)
//
#include <hip/hip_runtime.h>
#include <math.h>

#define NE 320000
#define NN 20000
#define NQ 200000

struct Prm {
  const float *x, *L0, *L1;
  const int *ei, *te;
  const float *W1, *b1, *W2, *b2, *wsim, *embs, *wod, *wL0, *wL1, *lin1W, *lin1b, *linW, *linb;
  float *out;
  int *ideg4, *start, *cnt, *cursor4, *csr;
  float *dinv, *h1raw, *h2raw, *g, *L0r, *L1r, *T0, *T1, *Bb, *Ab2, *Mm, *Ee, *semb, *Cpart;
};

// ---- 512^3 GEMM partial tile: C = A@B over K-slice [kbase, kbase+128) ----
__device__ __forceinline__ void gemm512_part(char* smem, const float* __restrict__ A,
                                             const float* __restrict__ B,
                                             float* __restrict__ C, int bb, int kbase) {
  float (*As)[68] = (float(*)[68])smem;
  float (*Bs)[68] = (float(*)[68])(smem + 16 * 68 * 4);
  int tid = threadIdx.x;
  int tx = tid & 15, ty = tid >> 4;
  int brow = (bb >> 3) * 64;
  int bcol = (bb & 7) * 64;
  int ar  = tid >> 2;
  int ac0 = (tid & 3) * 4;
  int br2 = tid >> 4;
  int bc0 = (tid & 15) * 4;
  float c[4][4] = {};
  for (int k0 = kbase; k0 < kbase + 128; k0 += 16) {
    float4 av = *(const float4*)&A[(size_t)(brow + ar) * 512 + k0 + ac0];
    float4 bv = *(const float4*)&B[(size_t)(k0 + br2) * 512 + bcol + bc0];
    As[ac0 + 0][ar] = av.x;
    As[ac0 + 1][ar] = av.y;
    As[ac0 + 2][ar] = av.z;
    As[ac0 + 3][ar] = av.w;
    *(float4*)&Bs[br2][bc0] = bv;
    __syncthreads();
#pragma unroll
    for (int k = 0; k < 16; k++) {
      float4 a = *(const float4*)&As[k][ty * 4];
      float4 b = *(const float4*)&Bs[k][tx * 4];
      c[0][0] = fmaf(a.x, b.x, c[0][0]); c[0][1] = fmaf(a.x, b.y, c[0][1]);
      c[0][2] = fmaf(a.x, b.z, c[0][2]); c[0][3] = fmaf(a.x, b.w, c[0][3]);
      c[1][0] = fmaf(a.y, b.x, c[1][0]); c[1][1] = fmaf(a.y, b.y, c[1][1]);
      c[1][2] = fmaf(a.y, b.z, c[1][2]); c[1][3] = fmaf(a.y, b.w, c[1][3]);
      c[2][0] = fmaf(a.z, b.x, c[2][0]); c[2][1] = fmaf(a.z, b.y, c[2][1]);
      c[2][2] = fmaf(a.z, b.z, c[2][2]); c[2][3] = fmaf(a.z, b.w, c[2][3]);
      c[3][0] = fmaf(a.w, b.x, c[3][0]); c[3][1] = fmaf(a.w, b.y, c[3][1]);
      c[3][2] = fmaf(a.w, b.z, c[3][2]); c[3][3] = fmaf(a.w, b.w, c[3][3]);
    }
    __syncthreads();
  }
#pragma unroll
  for (int i = 0; i < 4; i++) {
    float4 o;
    o.x = c[i][0]; o.y = c[i][1]; o.z = c[i][2]; o.w = c[i][3];
    *(float4*)&C[(size_t)(brow + ty * 4 + i) * 512 + bcol + tx * 4] = o;
  }
}

// ---- skinny GEMM, W staged in LDS in KC-row chunks (8KB): Y = X@W ----
template<int K, int N, int KC>
__device__ __forceinline__ void xw_chunk(char* smem, const float* __restrict__ X,
                                         const float* __restrict__ W,
                                         float* __restrict__ Y, int bb, int M) {
  constexpr int TPR = N / 4;
  constexpr int ROWS = 256 / TPR;
  float* Wl = (float*)smem;
  int r = bb * ROWS + threadIdx.x / TPR;
  int c4 = (threadIdx.x % TPR) * 4;
  float a0 = 0, a1 = 0, a2 = 0, a3 = 0;
#pragma unroll 1
  for (int k0 = 0; k0 < K; k0 += KC) {
    __syncthreads();
    for (int t = threadIdx.x; t < KC * N / 4; t += 256)
      ((float4*)Wl)[t] = ((const float4*)(W + k0 * N))[t];
    __syncthreads();
    if (r < M) {
      const float4* xr4 = (const float4*)(X + (size_t)r * K + k0);
#pragma unroll
      for (int k4 = 0; k4 < KC / 4; k4++) {
        float4 xv = xr4[k4];
        int kb = k4 * 4;
        { const float4 w = *(const float4*)&Wl[(kb + 0) * N + c4];
          a0 = fmaf(xv.x, w.x, a0); a1 = fmaf(xv.x, w.y, a1); a2 = fmaf(xv.x, w.z, a2); a3 = fmaf(xv.x, w.w, a3); }
        { const float4 w = *(const float4*)&Wl[(kb + 1) * N + c4];
          a0 = fmaf(xv.y, w.x, a0); a1 = fmaf(xv.y, w.y, a1); a2 = fmaf(xv.y, w.z, a2); a3 = fmaf(xv.y, w.w, a3); }
        { const float4 w = *(const float4*)&Wl[(kb + 2) * N + c4];
          a0 = fmaf(xv.z, w.x, a0); a1 = fmaf(xv.z, w.y, a1); a2 = fmaf(xv.z, w.z, a2); a3 = fmaf(xv.z, w.w, a3); }
        { const float4 w = *(const float4*)&Wl[(kb + 3) * N + c4];
          a0 = fmaf(xv.w, w.x, a0); a1 = fmaf(xv.w, w.y, a1); a2 = fmaf(xv.w, w.z, a2); a3 = fmaf(xv.w, w.w, a3); }
      }
    }
  }
  if (r < M) {
    float4 o; o.x = a0; o.y = a1; o.z = a2; o.w = a3;
    *(float4*)&Y[(size_t)r * N + c4] = o;
  }
}

// ---- Y(512x32) = X(512x512)@W(512x32), both streamed ----
__device__ __forceinline__ void sk512_body(const float* X, const float* W, float* Y, int b) {
  int r = b * 32 + threadIdx.x / 8;
  int c4 = (threadIdx.x % 8) * 4;
  const float4* xr4 = (const float4*)(X + (size_t)r * 512);
  float a0 = 0, a1 = 0, a2 = 0, a3 = 0;
#pragma unroll 2
  for (int k4 = 0; k4 < 128; k4++) {
    float4 xv = xr4[k4];
    int kb = k4 * 4;
    { const float4 w = *(const float4*)&W[(kb + 0) * 32 + c4];
      a0 = fmaf(xv.x, w.x, a0); a1 = fmaf(xv.x, w.y, a1); a2 = fmaf(xv.x, w.z, a2); a3 = fmaf(xv.x, w.w, a3); }
    { const float4 w = *(const float4*)&W[(kb + 1) * 32 + c4];
      a0 = fmaf(xv.y, w.x, a0); a1 = fmaf(xv.y, w.y, a1); a2 = fmaf(xv.y, w.z, a2); a3 = fmaf(xv.y, w.w, a3); }
    { const float4 w = *(const float4*)&W[(kb + 2) * 32 + c4];
      a0 = fmaf(xv.z, w.x, a0); a1 = fmaf(xv.z, w.y, a1); a2 = fmaf(xv.z, w.z, a2); a3 = fmaf(xv.z, w.w, a3); }
    { const float4 w = *(const float4*)&W[(kb + 3) * 32 + c4];
      a0 = fmaf(xv.w, w.x, a0); a1 = fmaf(xv.w, w.y, a1); a2 = fmaf(xv.w, w.z, a2); a3 = fmaf(xv.w, w.w, a3); }
  }
  float4 o; o.x = a0; o.y = a1; o.z = a2; o.w = a3;
  *(float4*)&Y[(size_t)r * 32 + c4] = o;
}

// ---- same, but X = sum of 4 K-split partial slices ----
__device__ __forceinline__ void sk512_sum4(const float* Xbase, size_t sstride4,
                                           const float* W, float* Y, int b) {
  int r = b * 32 + threadIdx.x / 8;
  int c4 = (threadIdx.x % 8) * 4;
  const float4* x0 = (const float4*)Xbase + (size_t)r * 128;
  float a0 = 0, a1 = 0, a2 = 0, a3 = 0;
#pragma unroll 2
  for (int k4 = 0; k4 < 128; k4++) {
    float4 xa = x0[k4];
    float4 xb = x0[sstride4 + k4];
    float4 xc = x0[2 * sstride4 + k4];
    float4 xd = x0[3 * sstride4 + k4];
    float4 xv;
    xv.x = xa.x + xb.x + xc.x + xd.x;
    xv.y = xa.y + xb.y + xc.y + xd.y;
    xv.z = xa.z + xb.z + xc.z + xd.z;
    xv.w = xa.w + xb.w + xc.w + xd.w;
    int kb = k4 * 4;
    { const float4 w = *(const float4*)&W[(kb + 0) * 32 + c4];
      a0 = fmaf(xv.x, w.x, a0); a1 = fmaf(xv.x, w.y, a1); a2 = fmaf(xv.x, w.z, a2); a3 = fmaf(xv.x, w.w, a3); }
    { const float4 w = *(const float4*)&W[(kb + 1) * 32 + c4];
      a0 = fmaf(xv.y, w.x, a0); a1 = fmaf(xv.y, w.y, a1); a2 = fmaf(xv.y, w.z, a2); a3 = fmaf(xv.y, w.w, a3); }
    { const float4 w = *(const float4*)&W[(kb + 2) * 32 + c4];
      a0 = fmaf(xv.z, w.x, a0); a1 = fmaf(xv.z, w.y, a1); a2 = fmaf(xv.z, w.z, a2); a3 = fmaf(xv.z, w.w, a3); }
    { const float4 w = *(const float4*)&W[(kb + 3) * 32 + c4];
      a0 = fmaf(xv.w, w.x, a0); a1 = fmaf(xv.w, w.y, a1); a2 = fmaf(xv.w, w.z, a2); a3 = fmaf(xv.w, w.w, a3); }
  }
  float4 o; o.x = a0; o.y = a1; o.z = a2; o.w = a3;
  *(float4*)&Y[(size_t)r * 32 + c4] = o;
}

// ================= kernels =================
// Cpart layout: slice s in [0,4) x { g=0: L0@L0, g=1: L1@L1, g=2: wod@L0 } x 512x512
#define CP_G 262144
#define CP_S 786432

// K1a: gemm partials (768) | T0,T1 (32)    [diagnostic split of old k1]
__global__ __launch_bounds__(256) void k1a(Prm p) {
  __shared__ __align__(16) char smem[8704];
  int b = blockIdx.x;
  if (b < 768) {
    int slice = b & 3, tile = (b >> 2) & 63, g = b >> 8;
    const float* A = (g == 0) ? p.L0 : (g == 1) ? p.L1 : p.wod;
    const float* B = (g == 1) ? p.L1 : p.L0;
    float* C = p.Cpart + (size_t)slice * CP_S + (size_t)g * CP_G;
    gemm512_part(smem, A, B, C, tile, slice * 128);
  }
  else if (b < 784) sk512_body(p.L0, p.wL0, p.T0, b - 768);
  else              sk512_body(p.L1, p.wL1, p.T1, b - 784);
}

// K1b: xw1 chunked-LDS (1250)
__global__ __launch_bounds__(256) void k1b(Prm p) {
  __shared__ __align__(16) char smem[8704];
  xw_chunk<128, 64, 32>(smem, p.x, p.W1, p.h1raw, blockIdx.x, NN);
}

// K1c: hist 4-replica (1250)
__global__ __launch_bounds__(256) void k1c(Prm p) {
  int m = blockIdx.x;                  // edge-chunk index
  int rep = m & 3;                     // replica (matches k3's chunk-relative map)
  int e = m * 256 + threadIdx.x;
  if (e < NE) atomicAdd(&p.ideg4[rep * NN + p.ei[NE + e]], 1);
}

// K2: reduce L0r||L1r (512) | Ab2 (16) | Bb (16) | scan+cursor4 (1, no reg-array)
__global__ __launch_bounds__(256) void k2(Prm p) {
  int b = blockIdx.x;
  int tid = threadIdx.x;
  if (b < 512) {
    int i4 = b * 256 + tid;
    const float4* cp = (const float4*)p.Cpart;
    float4 a = cp[i4];
    float4 b1 = cp[CP_S / 4 + i4];
    float4 c = cp[2 * (CP_S / 4) + i4];
    float4 d = cp[3 * (CP_S / 4) + i4];
    float4 o;
    o.x = a.x + b1.x + c.x + d.x;
    o.y = a.y + b1.y + c.y + d.y;
    o.z = a.z + b1.z + c.z + d.z;
    o.w = a.w + b1.w + c.w + d.w;
    ((float4*)p.L0r)[i4] = o;
    return;
  }
  if (b < 528) { sk512_sum4(p.Cpart + 2 * CP_G, CP_S / 4, p.T0, p.Ab2, b - 512); return; }
  if (b < 544) { sk512_body(p.L1, p.T1, p.Bb, b - 528); return; }
  // ---- scan over 4-replica counts (pass1: sum only; pass2: re-read + emit) ----
  __shared__ int wsum[4];
  int base = tid * 80;
  const int4* i0 = (const int4*)(p.ideg4)            + tid * 20;
  const int4* i1 = (const int4*)(p.ideg4 + NN)       + tid * 20;
  const int4* i2 = (const int4*)(p.ideg4 + 2 * NN)   + tid * 20;
  const int4* i3 = (const int4*)(p.ideg4 + 3 * NN)   + tid * 20;
  int s = 0;
  if (base < NN) {
#pragma unroll
    for (int i = 0; i < 20; i++) {
      int4 a = i0[i], b1 = i1[i], c = i2[i], d = i3[i];
      s += a.x + a.y + a.z + a.w + b1.x + b1.y + b1.z + b1.w
         + c.x + c.y + c.z + c.w + d.x + d.y + d.z + d.w;
    }
  }
  int lane = tid & 63, wid = tid >> 6;
  int v = s;
#pragma unroll
  for (int o = 1; o < 64; o <<= 1) { int u = __shfl_up(v, o); if (lane >= o) v += u; }
  if (lane == 63) wsum[wid] = v;
  __syncthreads();
  int wbase = 0;
  for (int w = 0; w < wid; w++) wbase += wsum[w];
  int off = wbase + v - s;
  if (base < NN) {
#pragma unroll
    for (int i = 0; i < 20; i++) {      // FULL unroll: static indexing, no scratch
      int4 a = i0[i], b1 = i1[i], c = i2[i], d = i3[i];   // L2-hot re-reads
      int4 t;
      t.x = a.x + b1.x + c.x + d.x;
      t.y = a.y + b1.y + c.y + d.y;
      t.z = a.z + b1.z + c.z + d.z;
      t.w = a.w + b1.w + c.w + d.w;
      int4 st, cu0, cu1, cu2, cu3;
      st.x = off; cu0.x = off; cu1.x = off + a.x; cu2.x = cu1.x + b1.x; cu3.x = cu2.x + c.x; off += t.x;
      st.y = off; cu0.y = off; cu1.y = off + a.y; cu2.y = cu1.y + b1.y; cu3.y = cu2.y + c.y; off += t.y;
      st.z = off; cu0.z = off; cu1.z = off + a.z; cu2.z = cu1.z + b1.z; cu3.z = cu2.z + c.z; off += t.z;
      st.w = off; cu0.w = off; cu1.w = off + a.w; cu2.w = cu1.w + b1.w; cu3.w = cu2.w + c.w; off += t.w;
      ((int4*)p.start)[tid * 20 + i] = st;
      ((int4*)p.cnt)[tid * 20 + i] = t;
      ((int4*)(p.cursor4))[tid * 20 + i] = cu0;
      ((int4*)(p.cursor4 + NN))[tid * 20 + i] = cu1;
      ((int4*)(p.cursor4 + 2 * NN))[tid * 20 + i] = cu2;
      ((int4*)(p.cursor4 + 3 * NN))[tid * 20 + i] = cu3;
      float4 dv;
      dv.x = rsqrtf((float)(t.x + 1));
      dv.y = rsqrtf((float)(t.y + 1));
      dv.z = rsqrtf((float)(t.z + 1));
      dv.w = rsqrtf((float)(t.w + 1));
      ((float4*)p.dinv)[tid * 20 + i] = dv;
    }
  }
}

// K3: softmaxM with fused rel_ (0..1023) | scatter 4-replica (1024..2273)
__global__ __launch_bounds__(256) void k3(Prm p) {
  int b = blockIdx.x;
  int tid = threadIdx.x;
  if (b >= 1024) {
    int m = b - 1024;
    int rep = m & 3;
    int e = m * 256 + tid;
    if (e < NE) {
      int d = p.ei[NE + e];
      int pos = atomicAdd(&p.cursor4[rep * NN + d], 1);
      p.csr[pos] = p.ei[e];
    }
    return;
  }
  int i = b;
  __shared__ float smax[4];
  __shared__ float sred[4][9];
  float urow[32];
  {
    const float4* up = (const float4*)((i < 512) ? (p.Ab2 + i * 32) : (p.Bb + (i - 512) * 32));
#pragma unroll
    for (int q = 0; q < 8; q++) {
      float4 u4 = up[q];
      urow[q * 4 + 0] = u4.x; urow[q * 4 + 1] = u4.y;
      urow[q * 4 + 2] = u4.z; urow[q * 4 + 3] = u4.w;
    }
  }
  float loc[4];
  float mymax = 0.0f;  // post-relu >= 0
#pragma unroll
  for (int tt = 0; tt < 4; tt++) {
    int j = tid + tt * 256;
    float v;
    if (i < 512) {
      if (j < 512) v = p.L0r[i * 512 + j];
      else {
        const float4* bj = (const float4*)(p.Bb + (j - 512) * 32);
        float acc = 0.0f;
#pragma unroll
        for (int q = 0; q < 8; q++) {
          float4 b4 = bj[q];
          acc = fmaf(urow[q * 4 + 0], b4.x, acc); acc = fmaf(urow[q * 4 + 1], b4.y, acc);
          acc = fmaf(urow[q * 4 + 2], b4.z, acc); acc = fmaf(urow[q * 4 + 3], b4.w, acc);
        }
        v = acc;
      }
    } else {
      int r = i - 512;
      if (j < 512) {
        const float4* aj = (const float4*)(p.Ab2 + j * 32);
        float acc = 0.0f;
#pragma unroll
        for (int q = 0; q < 8; q++) {
          float4 a4 = aj[q];
          acc = fmaf(urow[q * 4 + 0], a4.x, acc); acc = fmaf(urow[q * 4 + 1], a4.y, acc);
          acc = fmaf(urow[q * 4 + 2], a4.z, acc); acc = fmaf(urow[q * 4 + 3], a4.w, acc);
        }
        v = acc;
      } else v = p.L1r[r * 512 + (j - 512)];
    }
    v = fmaxf(v, 0.0f);
    loc[tt] = v;
    mymax = fmaxf(mymax, v);
  }
#pragma unroll
  for (int o = 32; o > 0; o >>= 1) mymax = fmaxf(mymax, __shfl_down(mymax, o));
  int wid = tid >> 6, lane = tid & 63;
  if (lane == 0) smax[wid] = mymax;
  __syncthreads();
  float m = fmaxf(fmaxf(smax[0], smax[1]), fmaxf(smax[2], smax[3]));

  float z = 0.0f, pm[8] = {};
#pragma unroll
  for (int tt = 0; tt < 4; tt++) {
    int j = tid + tt * 256;
    float e = __expf(loc[tt] - m);
    z += e;
    const float* wr = p.wsim + j * 8;
#pragma unroll
    for (int d = 0; d < 8; d++) pm[d] = fmaf(e, wr[d], pm[d]);
  }
#pragma unroll
  for (int o = 32; o > 0; o >>= 1) {
    z += __shfl_down(z, o);
#pragma unroll
    for (int d = 0; d < 8; d++) pm[d] += __shfl_down(pm[d], o);
  }
  if (lane == 0) {
    sred[wid][0] = z;
#pragma unroll
    for (int d = 0; d < 8; d++) sred[wid][1 + d] = pm[d];
  }
  __syncthreads();
  if (tid < 8) {
    float zt = sred[0][0] + sred[1][0] + sred[2][0] + sred[3][0];
    float pt = sred[0][1 + tid] + sred[1][1 + tid] + sred[2][1 + tid] + sred[3][1 + tid];
    p.Mm[i * 8 + tid] = pt / zt;
  }
}

// K4: gather64 (4 slots) + fused xw2 (5000) | E (32)
__global__ __launch_bounds__(256) void k4(Prm p) {
  __shared__ float W2l[64 * 32];
  __shared__ float h1l[4][64];
  int b = blockIdx.x;
  int tid = threadIdx.x;
  if (b < 5000) {
    for (int u = tid; u < 512; u += 256)
      ((float4*)W2l)[u] = ((const float4*)p.W2)[u];
    __syncthreads();
    int w = tid >> 6;
    int lane = tid & 63;
    int slot = lane >> 4;
    int fi = lane & 15;
    int n = b * 4 + w;
    int s0 = p.start[n], cnt = p.cnt[n];
    float4 acc = {0.f, 0.f, 0.f, 0.f};
    for (int k = 0; k < cnt; k += 4) {
      int kk = k + slot;
      bool valid = kk < cnt;
      int src = valid ? p.csr[s0 + kk] : n;
      float wgt = valid ? p.dinv[src] : 0.0f;
      float4 v = ((const float4*)(p.h1raw + (size_t)src * 64))[fi];
      acc.x = fmaf(v.x, wgt, acc.x); acc.y = fmaf(v.y, wgt, acc.y);
      acc.z = fmaf(v.z, wgt, acc.z); acc.w = fmaf(v.w, wgt, acc.w);
    }
    acc.x += __shfl_xor(acc.x, 16); acc.y += __shfl_xor(acc.y, 16);
    acc.z += __shfl_xor(acc.z, 16); acc.w += __shfl_xor(acc.w, 16);
    acc.x += __shfl_xor(acc.x, 32); acc.y += __shfl_xor(acc.y, 32);
    acc.z += __shfl_xor(acc.z, 32); acc.w += __shfl_xor(acc.w, 32);
    float dn = p.dinv[n];
    float4 self = ((const float4*)(p.h1raw + (size_t)n * 64))[fi];
    float4 b1q = ((const float4*)p.b1)[fi];
    float4 h;
    h.x = fmaxf(fmaf(acc.x, dn, self.x * dn * dn) + b1q.x, 0.0f);
    h.y = fmaxf(fmaf(acc.y, dn, self.y * dn * dn) + b1q.y, 0.0f);
    h.z = fmaxf(fmaf(acc.z, dn, self.z * dn * dn) + b1q.z, 0.0f);
    h.w = fmaxf(fmaf(acc.w, dn, self.w * dn * dn) + b1q.w, 0.0f);
    if (slot == 0) ((float4*)h1l[w])[fi] = h;
    __syncthreads();
    int c = lane & 31, half = lane >> 5;
    float s = 0.0f;
    const float* hr = h1l[w];
#pragma unroll
    for (int kk2 = 0; kk2 < 32; kk2++) {
      int k = half * 32 + kk2;
      s = fmaf(hr[k], W2l[k * 32 + c], s);
    }
    s += __shfl_xor(s, 32);
    if (half == 0) p.h2raw[(size_t)n * 32 + c] = s;
    return;
  }
  int lane = tid & 63;
  int r = (b - 5000) * 4 + (tid >> 6);
  const float* er = p.embs + (size_t)r * 1024;
  float acc[8] = {};
  for (int it = 0; it < 16; it++) {
    int k = lane + it * 64;
    float e = er[k];
    const float4* mp = (const float4*)&p.Mm[k * 8];
    float4 m0 = mp[0], m1 = mp[1];
    acc[0] = fmaf(e, m0.x, acc[0]); acc[1] = fmaf(e, m0.y, acc[1]);
    acc[2] = fmaf(e, m0.z, acc[2]); acc[3] = fmaf(e, m0.w, acc[3]);
    acc[4] = fmaf(e, m1.x, acc[4]); acc[5] = fmaf(e, m1.y, acc[5]);
    acc[6] = fmaf(e, m1.z, acc[6]); acc[7] = fmaf(e, m1.w, acc[7]);
  }
#pragma unroll
  for (int o = 32; o > 0; o >>= 1)
#pragma unroll
    for (int d = 0; d < 8; d++) acc[d] += __shfl_down(acc[d], o);
  if (lane == 0)
#pragma unroll
    for (int d = 0; d < 8; d++) p.Ee[r * 8 + d] = acc[d];
}

// K5: gather32 (8 slots) + renorm (5000) | semb (79)
__global__ __launch_bounds__(256) void k5(Prm p) {
  __shared__ float El[1024];
  int b = blockIdx.x;
  int tid = threadIdx.x;
  if (b < 5000) {
    int w = tid >> 6;
    int lane = tid & 63;
    int slot = lane >> 3;
    int fi = lane & 7;
    int n = b * 4 + w;
    int s0 = p.start[n], cnt = p.cnt[n];
    float4 acc = {0.f, 0.f, 0.f, 0.f};
    for (int k = 0; k < cnt; k += 8) {
      int kk = k + slot;
      bool valid = kk < cnt;
      int src = valid ? p.csr[s0 + kk] : n;
      float wgt = valid ? p.dinv[src] : 0.0f;
      float4 v = ((const float4*)(p.h2raw + (size_t)src * 32))[fi];
      acc.x = fmaf(v.x, wgt, acc.x); acc.y = fmaf(v.y, wgt, acc.y);
      acc.z = fmaf(v.z, wgt, acc.z); acc.w = fmaf(v.w, wgt, acc.w);
    }
    acc.x += __shfl_xor(acc.x, 8);  acc.y += __shfl_xor(acc.y, 8);
    acc.z += __shfl_xor(acc.z, 8);  acc.w += __shfl_xor(acc.w, 8);
    acc.x += __shfl_xor(acc.x, 16); acc.y += __shfl_xor(acc.y, 16);
    acc.z += __shfl_xor(acc.z, 16); acc.w += __shfl_xor(acc.w, 16);
    acc.x += __shfl_xor(acc.x, 32); acc.y += __shfl_xor(acc.y, 32);
    acc.z += __shfl_xor(acc.z, 32); acc.w += __shfl_xor(acc.w, 32);
    float dn = p.dinv[n];
    float4 self = ((const float4*)(p.h2raw + (size_t)n * 32))[fi];
    float4 b2q = ((const float4*)p.b2)[fi];
    float4 h;
    h.x = fmaxf(fmaf(acc.x, dn, self.x * dn * dn) + b2q.x, 0.0f);
    h.y = fmaxf(fmaf(acc.y, dn, self.y * dn * dn) + b2q.y, 0.0f);
    h.z = fmaxf(fmaf(acc.z, dn, self.z * dn * dn) + b2q.z, 0.0f);
    h.w = fmaxf(fmaf(acc.w, dn, self.w * dn * dn) + b2q.w, 0.0f);
    float n2 = h.x * h.x + h.y * h.y + h.z * h.z + h.w * h.w;
    n2 += __shfl_xor(n2, 1); n2 += __shfl_xor(n2, 2); n2 += __shfl_xor(n2, 4);
    float nrm = sqrtf(n2);
    float sc = (nrm > 1.0f) ? 1.0f / (nrm + 1e-7f) : 1.0f;
    if (slot == 0) {
      float4 o; o.x = h.x * sc; o.y = h.y * sc; o.z = h.z * sc; o.w = h.w * sc;
      ((float4*)(p.g + (size_t)n * 32))[fi] = o;
    }
    return;
  }
  for (int u = tid; u < 256; u += 256)
    ((float4*)El)[u] = ((const float4*)p.Ee)[u];
  __syncthreads();
  int row = (b - 5000) * 256 + tid;
  if (row >= NN) return;
  const float4* xr4 = (const float4*)(p.x + (size_t)row * 128);
  float s[8] = {};
#pragma unroll 4
  for (int k4 = 0; k4 < 32; k4++) {
    float4 xv = xr4[k4];
    int kb = k4 * 4;
#pragma unroll
    for (int u = 0; u < 4; u++) {
      float xk = (u == 0) ? xv.x : (u == 1) ? xv.y : (u == 2) ? xv.z : xv.w;
      const float4* ep = (const float4*)&El[(kb + u) * 8];
      float4 e0 = ep[0], e1 = ep[1];
      s[0] = fmaf(xk, e0.x, s[0]); s[1] = fmaf(xk, e0.y, s[1]);
      s[2] = fmaf(xk, e0.z, s[2]); s[3] = fmaf(xk, e0.w, s[3]);
      s[4] = fmaf(xk, e1.x, s[4]); s[5] = fmaf(xk, e1.y, s[5]);
      s[6] = fmaf(xk, e1.z, s[6]); s[7] = fmaf(xk, e1.w, s[7]);
    }
  }
  float n2 = 0.0f;
#pragma unroll
  for (int d = 0; d < 8; d++) n2 += s[d] * s[d];
  float n = sqrtf(n2);
  float sc = (n > 1.0f) ? 1.0f / (n + 1e-7f) : 1.0f;
#pragma unroll
  for (int d = 0; d < 8; d++) p.semb[(size_t)row * 8 + d] = s[d] * sc;
}

// K6: query head (782)
__global__ __launch_bounds__(256) void k6(Prm p) {
  int q = blockIdx.x * 256 + threadIdx.x;
  if (q >= NQ) return;
  const int2 pr = ((const int2*)p.te)[q];
  int i0 = pr.x, i1 = pr.y;
  float feat[40];
  const float4* g0 = (const float4*)(p.g + (size_t)i0 * 32);
  const float4* g1 = (const float4*)(p.g + (size_t)i1 * 32);
#pragma unroll
  for (int u = 0; u < 8; u++) {
    float4 a = g0[u], b = g1[u];
    float d0 = a.x - b.x, d1 = a.y - b.y, d2 = a.z - b.z, d3 = a.w - b.w;
    feat[u * 4 + 0] = d0 * d0; feat[u * 4 + 1] = d1 * d1;
    feat[u * 4 + 2] = d2 * d2; feat[u * 4 + 3] = d3 * d3;
  }
  const float4* s0 = (const float4*)(p.semb + (size_t)i0 * 8);
  const float4* s1 = (const float4*)(p.semb + (size_t)i1 * 8);
#pragma unroll
  for (int u = 0; u < 2; u++) {
    float4 a = s0[u], b = s1[u];
    float d0 = a.x - b.x, d1 = a.y - b.y, d2 = a.z - b.z, d3 = a.w - b.w;
    feat[32 + u * 4 + 0] = 0.1f * d0 * d0; feat[32 + u * 4 + 1] = 0.1f * d1 * d1;
    feat[32 + u * 4 + 2] = 0.1f * d2 * d2; feat[32 + u * 4 + 3] = 0.1f * d3 * d3;
  }
  float acc[32];
#pragma unroll
  for (int c = 0; c < 32; c++) acc[c] = p.lin1b[c];
#pragma unroll
  for (int k = 0; k < 40; k++) {
    float f = feat[k];
#pragma unroll
    for (int c = 0; c < 32; c++) acc[c] = fmaf(f, p.lin1W[k * 32 + c], acc[c]);
  }
  float accv = p.linb[0];
#pragma unroll
  for (int c = 0; c < 32; c++) {
    float a = acc[c];
    a = (a > 0.0f) ? a : 0.2f * a;
    accv = fmaf(a, p.linW[c], accv);
  }
  float sq = fminf(fabsf(accv), 40.0f);
  p.out[q] = 1.0f / (1.0f + __expf(sq - 2.0f));
}

extern "C" void kernel_launch(void* const* d_in, const int* in_sizes, int n_in,
                              void* d_out, int out_size, void* d_ws, size_t ws_size,
                              hipStream_t stream) {
  Prm p;
  p.x     = (const float*)d_in[0];
  p.L0    = (const float*)d_in[1];
  p.L1    = (const float*)d_in[2];
  p.ei    = (const int*)d_in[3];
  p.te    = (const int*)d_in[4];
  p.W1    = (const float*)d_in[5];
  p.b1    = (const float*)d_in[6];
  p.W2    = (const float*)d_in[7];
  p.b2    = (const float*)d_in[8];
  p.wsim  = (const float*)d_in[9];
  p.embs  = (const float*)d_in[10];
  p.wod   = (const float*)d_in[11];
  p.wL0   = (const float*)d_in[12];
  p.wL1   = (const float*)d_in[13];
  p.lin1W = (const float*)d_in[14];
  p.lin1b = (const float*)d_in[15];
  p.linW  = (const float*)d_in[16];
  p.linb  = (const float*)d_in[17];
  p.out   = (float*)d_out;

  p.ideg4   = (int*)d_ws;                   // 80,000 (4 x 20000)
  p.start   = p.ideg4 + 80000;              // 20,000
  p.cnt     = p.start + 20000;              // 20,000
  p.cursor4 = p.cnt + 20000;                // 80,000 (4 x 20000)
  p.csr     = p.cursor4 + 80000;            // 320,000
  p.dinv    = (float*)(p.csr + 320000);     // 20,000
  p.h1raw   = p.dinv + 20000;               // 1,280,000
  p.h2raw   = p.h1raw + 1280000;            // 640,000
  p.g       = p.h2raw + 640000;             // 640,000
  p.L0r     = p.g + 640000;                 // 262,144
  p.L1r     = p.L0r + 262144;               // 262,144 (contiguous with L0r)
  p.T0      = p.L1r + 262144;               // 16,384
  p.T1      = p.T0 + 16384;                 // 16,384
  p.Bb      = p.T1 + 16384;                 // 16,384
  p.Ab2     = p.Bb + 16384;                 // 16,384
  p.Mm      = p.Ab2 + 16384;                // 8,192
  p.Ee      = p.Mm + 8192;                  // 1,024
  p.semb    = p.Ee + 1024;                  // 160,000
  p.Cpart   = p.semb + 160000;              // 3,145,728 (4 slices x 3 x 512x512)

  hipMemsetAsync(p.ideg4, 0, 80000 * sizeof(int), stream);
  k1a<<<800,  256, 0, stream>>>(p);
  k1b<<<1250, 256, 0, stream>>>(p);
  k1c<<<1250, 256, 0, stream>>>(p);
  k2<<<545,   256, 0, stream>>>(p);
  k3<<<2274,  256, 0, stream>>>(p);
  k4<<<5032,  256, 0, stream>>>(p);
  k5<<<5079,  256, 0, stream>>>(p);
  k6<<<782,   256, 0, stream>>>(p);
}

// Round 14
// 179.420 us; speedup vs baseline: 1.1291x; 1.1291x over previous
//
#include <hip/hip_runtime.h>
#include <math.h>

#define NE 320000
#define NN 20000
#define NQ 200000

struct Prm {
  const float *x, *L0, *L1;
  const int *ei, *te;
  const float *W1, *b1, *W2, *b2, *wsim, *embs, *wod, *wL0, *wL1, *lin1W, *lin1b, *linW, *linb;
  float *out;
  int *ideg, *start, *cursor, *csr;
  float *dinv, *h1raw, *h2raw, *g, *L0r, *L1r, *T0, *T1, *Bb, *Ab2, *Mm, *Ee, *semb, *Cpart;
};

// ---- 512^3 GEMM partial tile: C = A@B over K-slice [kbase, kbase+128) ----
__device__ __forceinline__ void gemm512_part(char* smem, const float* __restrict__ A,
                                             const float* __restrict__ B,
                                             float* __restrict__ C, int bb, int kbase) {
  float (*As)[68] = (float(*)[68])smem;
  float (*Bs)[68] = (float(*)[68])(smem + 16 * 68 * 4);
  int tid = threadIdx.x;
  int tx = tid & 15, ty = tid >> 4;
  int brow = (bb >> 3) * 64;
  int bcol = (bb & 7) * 64;
  int ar  = tid >> 2;
  int ac0 = (tid & 3) * 4;
  int br2 = tid >> 4;
  int bc0 = (tid & 15) * 4;
  float c[4][4] = {};
  for (int k0 = kbase; k0 < kbase + 128; k0 += 16) {
    float4 av = *(const float4*)&A[(size_t)(brow + ar) * 512 + k0 + ac0];
    float4 bv = *(const float4*)&B[(size_t)(k0 + br2) * 512 + bcol + bc0];
    As[ac0 + 0][ar] = av.x;
    As[ac0 + 1][ar] = av.y;
    As[ac0 + 2][ar] = av.z;
    As[ac0 + 3][ar] = av.w;
    *(float4*)&Bs[br2][bc0] = bv;
    __syncthreads();
#pragma unroll
    for (int k = 0; k < 16; k++) {
      float4 a = *(const float4*)&As[k][ty * 4];
      float4 b = *(const float4*)&Bs[k][tx * 4];
      c[0][0] = fmaf(a.x, b.x, c[0][0]); c[0][1] = fmaf(a.x, b.y, c[0][1]);
      c[0][2] = fmaf(a.x, b.z, c[0][2]); c[0][3] = fmaf(a.x, b.w, c[0][3]);
      c[1][0] = fmaf(a.y, b.x, c[1][0]); c[1][1] = fmaf(a.y, b.y, c[1][1]);
      c[1][2] = fmaf(a.y, b.z, c[1][2]); c[1][3] = fmaf(a.y, b.w, c[1][3]);
      c[2][0] = fmaf(a.z, b.x, c[2][0]); c[2][1] = fmaf(a.z, b.y, c[2][1]);
      c[2][2] = fmaf(a.z, b.z, c[2][2]); c[2][3] = fmaf(a.z, b.w, c[2][3]);
      c[3][0] = fmaf(a.w, b.x, c[3][0]); c[3][1] = fmaf(a.w, b.y, c[3][1]);
      c[3][2] = fmaf(a.w, b.z, c[3][2]); c[3][3] = fmaf(a.w, b.w, c[3][3]);
    }
    __syncthreads();
  }
#pragma unroll
  for (int i = 0; i < 4; i++) {
    float4 o;
    o.x = c[i][0]; o.y = c[i][1]; o.z = c[i][2]; o.w = c[i][3];
    *(float4*)&C[(size_t)(brow + ty * 4 + i) * 512 + bcol + tx * 4] = o;
  }
}

// ---- skinny GEMM, W staged in LDS in KC-row chunks (8KB): Y = X@W ----
template<int K, int N, int KC>
__device__ __forceinline__ void xw_chunk(char* smem, const float* __restrict__ X,
                                         const float* __restrict__ W,
                                         float* __restrict__ Y, int bb, int M) {
  constexpr int TPR = N / 4;
  constexpr int ROWS = 256 / TPR;
  float* Wl = (float*)smem;
  int r = bb * ROWS + threadIdx.x / TPR;
  int c4 = (threadIdx.x % TPR) * 4;
  float a0 = 0, a1 = 0, a2 = 0, a3 = 0;
#pragma unroll 1
  for (int k0 = 0; k0 < K; k0 += KC) {
    __syncthreads();
    for (int t = threadIdx.x; t < KC * N / 4; t += 256)
      ((float4*)Wl)[t] = ((const float4*)(W + k0 * N))[t];
    __syncthreads();
    if (r < M) {
      const float4* xr4 = (const float4*)(X + (size_t)r * K + k0);
#pragma unroll
      for (int k4 = 0; k4 < KC / 4; k4++) {
        float4 xv = xr4[k4];
        int kb = k4 * 4;
        { const float4 w = *(const float4*)&Wl[(kb + 0) * N + c4];
          a0 = fmaf(xv.x, w.x, a0); a1 = fmaf(xv.x, w.y, a1); a2 = fmaf(xv.x, w.z, a2); a3 = fmaf(xv.x, w.w, a3); }
        { const float4 w = *(const float4*)&Wl[(kb + 1) * N + c4];
          a0 = fmaf(xv.y, w.x, a0); a1 = fmaf(xv.y, w.y, a1); a2 = fmaf(xv.y, w.z, a2); a3 = fmaf(xv.y, w.w, a3); }
        { const float4 w = *(const float4*)&Wl[(kb + 2) * N + c4];
          a0 = fmaf(xv.z, w.x, a0); a1 = fmaf(xv.z, w.y, a1); a2 = fmaf(xv.z, w.z, a2); a3 = fmaf(xv.z, w.w, a3); }
        { const float4 w = *(const float4*)&Wl[(kb + 3) * N + c4];
          a0 = fmaf(xv.w, w.x, a0); a1 = fmaf(xv.w, w.y, a1); a2 = fmaf(xv.w, w.z, a2); a3 = fmaf(xv.w, w.w, a3); }
      }
    }
  }
  if (r < M) {
    float4 o; o.x = a0; o.y = a1; o.z = a2; o.w = a3;
    *(float4*)&Y[(size_t)r * N + c4] = o;
  }
}

// ---- Y(512x32) = X(512x512)@W(512x32), both streamed ----
__device__ __forceinline__ void sk512_body(const float* X, const float* W, float* Y, int b) {
  int r = b * 32 + threadIdx.x / 8;
  int c4 = (threadIdx.x % 8) * 4;
  const float4* xr4 = (const float4*)(X + (size_t)r * 512);
  float a0 = 0, a1 = 0, a2 = 0, a3 = 0;
#pragma unroll 2
  for (int k4 = 0; k4 < 128; k4++) {
    float4 xv = xr4[k4];
    int kb = k4 * 4;
    { const float4 w = *(const float4*)&W[(kb + 0) * 32 + c4];
      a0 = fmaf(xv.x, w.x, a0); a1 = fmaf(xv.x, w.y, a1); a2 = fmaf(xv.x, w.z, a2); a3 = fmaf(xv.x, w.w, a3); }
    { const float4 w = *(const float4*)&W[(kb + 1) * 32 + c4];
      a0 = fmaf(xv.y, w.x, a0); a1 = fmaf(xv.y, w.y, a1); a2 = fmaf(xv.y, w.z, a2); a3 = fmaf(xv.y, w.w, a3); }
    { const float4 w = *(const float4*)&W[(kb + 2) * 32 + c4];
      a0 = fmaf(xv.z, w.x, a0); a1 = fmaf(xv.z, w.y, a1); a2 = fmaf(xv.z, w.z, a2); a3 = fmaf(xv.z, w.w, a3); }
    { const float4 w = *(const float4*)&W[(kb + 3) * 32 + c4];
      a0 = fmaf(xv.w, w.x, a0); a1 = fmaf(xv.w, w.y, a1); a2 = fmaf(xv.w, w.z, a2); a3 = fmaf(xv.w, w.w, a3); }
  }
  float4 o; o.x = a0; o.y = a1; o.z = a2; o.w = a3;
  *(float4*)&Y[(size_t)r * 32 + c4] = o;
}

// ---- same, but X = sum of 4 K-split partial slices ----
__device__ __forceinline__ void sk512_sum4(const float* Xbase, size_t sstride4,
                                           const float* W, float* Y, int b) {
  int r = b * 32 + threadIdx.x / 8;
  int c4 = (threadIdx.x % 8) * 4;
  const float4* x0 = (const float4*)Xbase + (size_t)r * 128;
  float a0 = 0, a1 = 0, a2 = 0, a3 = 0;
#pragma unroll 2
  for (int k4 = 0; k4 < 128; k4++) {
    float4 xa = x0[k4];
    float4 xb = x0[sstride4 + k4];
    float4 xc = x0[2 * sstride4 + k4];
    float4 xd = x0[3 * sstride4 + k4];
    float4 xv;
    xv.x = xa.x + xb.x + xc.x + xd.x;
    xv.y = xa.y + xb.y + xc.y + xd.y;
    xv.z = xa.z + xb.z + xc.z + xd.z;
    xv.w = xa.w + xb.w + xc.w + xd.w;
    int kb = k4 * 4;
    { const float4 w = *(const float4*)&W[(kb + 0) * 32 + c4];
      a0 = fmaf(xv.x, w.x, a0); a1 = fmaf(xv.x, w.y, a1); a2 = fmaf(xv.x, w.z, a2); a3 = fmaf(xv.x, w.w, a3); }
    { const float4 w = *(const float4*)&W[(kb + 1) * 32 + c4];
      a0 = fmaf(xv.y, w.x, a0); a1 = fmaf(xv.y, w.y, a1); a2 = fmaf(xv.y, w.z, a2); a3 = fmaf(xv.y, w.w, a3); }
    { const float4 w = *(const float4*)&W[(kb + 2) * 32 + c4];
      a0 = fmaf(xv.z, w.x, a0); a1 = fmaf(xv.z, w.y, a1); a2 = fmaf(xv.z, w.z, a2); a3 = fmaf(xv.z, w.w, a3); }
    { const float4 w = *(const float4*)&W[(kb + 3) * 32 + c4];
      a0 = fmaf(xv.w, w.x, a0); a1 = fmaf(xv.w, w.y, a1); a2 = fmaf(xv.w, w.z, a2); a3 = fmaf(xv.w, w.w, a3); }
  }
  float4 o; o.x = a0; o.y = a1; o.z = a2; o.w = a3;
  *(float4*)&Y[(size_t)r * 32 + c4] = o;
}

// ================= kernels =================
// Cpart layout: slice s in [0,4) x { g=0: L0@L0, g=1: L1@L1, g=2: wod@L0 } x 512x512
#define CP_G 262144
#define CP_S 786432

// K1a: gemm partials (768) | T0,T1 (32)
__global__ __launch_bounds__(256) void k1a(Prm p) {
  __shared__ __align__(16) char smem[8704];
  int b = blockIdx.x;
  if (b < 768) {
    int slice = b & 3, tile = (b >> 2) & 63, g = b >> 8;
    const float* A = (g == 0) ? p.L0 : (g == 1) ? p.L1 : p.wod;
    const float* B = (g == 1) ? p.L1 : p.L0;
    float* C = p.Cpart + (size_t)slice * CP_S + (size_t)g * CP_G;
    gemm512_part(smem, A, B, C, tile, slice * 128);
  }
  else if (b < 784) sk512_body(p.L0, p.wL0, p.T0, b - 768);
  else              sk512_body(p.L1, p.wL1, p.T1, b - 784);
}

// K1b: xw1 chunked-LDS (1250)
__global__ __launch_bounds__(256) void k1b(Prm p) {
  __shared__ __align__(16) char smem[8704];
  xw_chunk<128, 64, 32>(smem, p.x, p.W1, p.h1raw, blockIdx.x, NN);
}

// K1c: hist single-replica (1250)
__global__ __launch_bounds__(256) void k1c(Prm p) {
  int e = blockIdx.x * 256 + threadIdx.x;
  if (e < NE) atomicAdd(&p.ideg[p.ei[NE + e]], 1);
}

// K2: reduce L0r||L1r (512) | Ab2 (16) | Bb (16) | scan (1, round-10 form)
__global__ __launch_bounds__(256) void k2(Prm p) {
  int b = blockIdx.x;
  int tid = threadIdx.x;
  if (b < 512) {
    int i4 = b * 256 + tid;
    const float4* cp = (const float4*)p.Cpart;
    float4 a = cp[i4];
    float4 b1 = cp[CP_S / 4 + i4];
    float4 c = cp[2 * (CP_S / 4) + i4];
    float4 d = cp[3 * (CP_S / 4) + i4];
    float4 o;
    o.x = a.x + b1.x + c.x + d.x;
    o.y = a.y + b1.y + c.y + d.y;
    o.z = a.z + b1.z + c.z + d.z;
    o.w = a.w + b1.w + c.w + d.w;
    ((float4*)p.L0r)[i4] = o;
    return;
  }
  if (b < 528) { sk512_sum4(p.Cpart + 2 * CP_G, CP_S / 4, p.T0, p.Ab2, b - 512); return; }
  if (b < 544) { sk512_body(p.L1, p.T1, p.Bb, b - 528); return; }
  // ---- exclusive scan over 20000 degrees (round-10 form) ----
  __shared__ int wsum[4];
  int base = tid * 80;
  int4 c[20];
  int s = 0;
  if (base < NN) {
    const int4* ip = (const int4*)p.ideg + tid * 20;
#pragma unroll
    for (int i = 0; i < 20; i++) c[i] = ip[i];
#pragma unroll
    for (int i = 0; i < 20; i++) s += c[i].x + c[i].y + c[i].z + c[i].w;
  }
  int lane = tid & 63, wid = tid >> 6;
  int v = s;
#pragma unroll
  for (int o = 1; o < 64; o <<= 1) { int u = __shfl_up(v, o); if (lane >= o) v += u; }
  if (lane == 63) wsum[wid] = v;
  __syncthreads();
  int wbase = 0;
  for (int w = 0; w < wid; w++) wbase += wsum[w];
  int off = wbase + v - s;
  if (base < NN) {
#pragma unroll
    for (int i = 0; i < 20; i++) {
      int4 cc = c[i];
      int4 st;
      st.x = off; off += cc.x;
      st.y = off; off += cc.y;
      st.z = off; off += cc.z;
      st.w = off; off += cc.w;
      ((int4*)p.start)[tid * 20 + i] = st;
      ((int4*)p.cursor)[tid * 20 + i] = st;
      float4 dv;
      dv.x = rsqrtf((float)(cc.x + 1));
      dv.y = rsqrtf((float)(cc.y + 1));
      dv.z = rsqrtf((float)(cc.z + 1));
      dv.w = rsqrtf((float)(cc.w + 1));
      ((float4*)p.dinv)[tid * 20 + i] = dv;
    }
  }
}

// K3: softmaxM with fused rel_ (0..1023) | scatter (1024..2273)
__global__ __launch_bounds__(256) void k3(Prm p) {
  int b = blockIdx.x;
  int tid = threadIdx.x;
  if (b >= 1024) {
    int e = (b - 1024) * 256 + tid;
    if (e < NE) {
      int d = p.ei[NE + e];
      int pos = atomicAdd(&p.cursor[d], 1);
      p.csr[pos] = p.ei[e];
    }
    return;
  }
  int i = b;
  __shared__ float smax[4];
  __shared__ float sred[4][9];
  float urow[32];
  {
    const float4* up = (const float4*)((i < 512) ? (p.Ab2 + i * 32) : (p.Bb + (i - 512) * 32));
#pragma unroll
    for (int q = 0; q < 8; q++) {
      float4 u4 = up[q];
      urow[q * 4 + 0] = u4.x; urow[q * 4 + 1] = u4.y;
      urow[q * 4 + 2] = u4.z; urow[q * 4 + 3] = u4.w;
    }
  }
  float loc[4];
  float mymax = 0.0f;  // post-relu >= 0
#pragma unroll
  for (int tt = 0; tt < 4; tt++) {
    int j = tid + tt * 256;
    float v;
    if (i < 512) {
      if (j < 512) v = p.L0r[i * 512 + j];
      else {
        const float4* bj = (const float4*)(p.Bb + (j - 512) * 32);
        float acc = 0.0f;
#pragma unroll
        for (int q = 0; q < 8; q++) {
          float4 b4 = bj[q];
          acc = fmaf(urow[q * 4 + 0], b4.x, acc); acc = fmaf(urow[q * 4 + 1], b4.y, acc);
          acc = fmaf(urow[q * 4 + 2], b4.z, acc); acc = fmaf(urow[q * 4 + 3], b4.w, acc);
        }
        v = acc;
      }
    } else {
      int r = i - 512;
      if (j < 512) {
        const float4* aj = (const float4*)(p.Ab2 + j * 32);
        float acc = 0.0f;
#pragma unroll
        for (int q = 0; q < 8; q++) {
          float4 a4 = aj[q];
          acc = fmaf(urow[q * 4 + 0], a4.x, acc); acc = fmaf(urow[q * 4 + 1], a4.y, acc);
          acc = fmaf(urow[q * 4 + 2], a4.z, acc); acc = fmaf(urow[q * 4 + 3], a4.w, acc);
        }
        v = acc;
      } else v = p.L1r[r * 512 + (j - 512)];
    }
    v = fmaxf(v, 0.0f);
    loc[tt] = v;
    mymax = fmaxf(mymax, v);
  }
#pragma unroll
  for (int o = 32; o > 0; o >>= 1) mymax = fmaxf(mymax, __shfl_down(mymax, o));
  int wid = tid >> 6, lane = tid & 63;
  if (lane == 0) smax[wid] = mymax;
  __syncthreads();
  float m = fmaxf(fmaxf(smax[0], smax[1]), fmaxf(smax[2], smax[3]));

  float z = 0.0f, pm[8] = {};
#pragma unroll
  for (int tt = 0; tt < 4; tt++) {
    int j = tid + tt * 256;
    float e = __expf(loc[tt] - m);
    z += e;
    const float* wr = p.wsim + j * 8;
#pragma unroll
    for (int d = 0; d < 8; d++) pm[d] = fmaf(e, wr[d], pm[d]);
  }
#pragma unroll
  for (int o = 32; o > 0; o >>= 1) {
    z += __shfl_down(z, o);
#pragma unroll
    for (int d = 0; d < 8; d++) pm[d] += __shfl_down(pm[d], o);
  }
  if (lane == 0) {
    sred[wid][0] = z;
#pragma unroll
    for (int d = 0; d < 8; d++) sred[wid][1 + d] = pm[d];
  }
  __syncthreads();
  if (tid < 8) {
    float zt = sred[0][0] + sred[1][0] + sred[2][0] + sred[3][0];
    float pt = sred[0][1 + tid] + sred[1][1 + tid] + sred[2][1 + tid] + sred[3][1 + tid];
    p.Mm[i * 8 + tid] = pt / zt;
  }
}

// K4: gather64 (4 slots) + fused xw2 (5000) | E (32)
__global__ __launch_bounds__(256) void k4(Prm p) {
  __shared__ float W2l[64 * 32];
  __shared__ float h1l[4][64];
  int b = blockIdx.x;
  int tid = threadIdx.x;
  if (b < 5000) {
    for (int u = tid; u < 512; u += 256)
      ((float4*)W2l)[u] = ((const float4*)p.W2)[u];
    __syncthreads();
    int w = tid >> 6;
    int lane = tid & 63;
    int slot = lane >> 4;
    int fi = lane & 15;
    int n = b * 4 + w;
    int s0 = p.start[n], cnt = p.ideg[n];
    float4 acc = {0.f, 0.f, 0.f, 0.f};
    for (int k = 0; k < cnt; k += 4) {
      int kk = k + slot;
      bool valid = kk < cnt;
      int src = valid ? p.csr[s0 + kk] : n;
      float wgt = valid ? p.dinv[src] : 0.0f;
      float4 v = ((const float4*)(p.h1raw + (size_t)src * 64))[fi];
      acc.x = fmaf(v.x, wgt, acc.x); acc.y = fmaf(v.y, wgt, acc.y);
      acc.z = fmaf(v.z, wgt, acc.z); acc.w = fmaf(v.w, wgt, acc.w);
    }
    acc.x += __shfl_xor(acc.x, 16); acc.y += __shfl_xor(acc.y, 16);
    acc.z += __shfl_xor(acc.z, 16); acc.w += __shfl_xor(acc.w, 16);
    acc.x += __shfl_xor(acc.x, 32); acc.y += __shfl_xor(acc.y, 32);
    acc.z += __shfl_xor(acc.z, 32); acc.w += __shfl_xor(acc.w, 32);
    float dn = p.dinv[n];
    float4 self = ((const float4*)(p.h1raw + (size_t)n * 64))[fi];
    float4 b1q = ((const float4*)p.b1)[fi];
    float4 h;
    h.x = fmaxf(fmaf(acc.x, dn, self.x * dn * dn) + b1q.x, 0.0f);
    h.y = fmaxf(fmaf(acc.y, dn, self.y * dn * dn) + b1q.y, 0.0f);
    h.z = fmaxf(fmaf(acc.z, dn, self.z * dn * dn) + b1q.z, 0.0f);
    h.w = fmaxf(fmaf(acc.w, dn, self.w * dn * dn) + b1q.w, 0.0f);
    if (slot == 0) ((float4*)h1l[w])[fi] = h;
    __syncthreads();
    int c = lane & 31, half = lane >> 5;
    float s = 0.0f;
    const float* hr = h1l[w];
#pragma unroll
    for (int kk2 = 0; kk2 < 32; kk2++) {
      int k = half * 32 + kk2;
      s = fmaf(hr[k], W2l[k * 32 + c], s);
    }
    s += __shfl_xor(s, 32);
    if (half == 0) p.h2raw[(size_t)n * 32 + c] = s;
    return;
  }
  int lane = tid & 63;
  int r = (b - 5000) * 4 + (tid >> 6);
  const float* er = p.embs + (size_t)r * 1024;
  float acc[8] = {};
  for (int it = 0; it < 16; it++) {
    int k = lane + it * 64;
    float e = er[k];
    const float4* mp = (const float4*)&p.Mm[k * 8];
    float4 m0 = mp[0], m1 = mp[1];
    acc[0] = fmaf(e, m0.x, acc[0]); acc[1] = fmaf(e, m0.y, acc[1]);
    acc[2] = fmaf(e, m0.z, acc[2]); acc[3] = fmaf(e, m0.w, acc[3]);
    acc[4] = fmaf(e, m1.x, acc[4]); acc[5] = fmaf(e, m1.y, acc[5]);
    acc[6] = fmaf(e, m1.z, acc[6]); acc[7] = fmaf(e, m1.w, acc[7]);
  }
#pragma unroll
  for (int o = 32; o > 0; o >>= 1)
#pragma unroll
    for (int d = 0; d < 8; d++) acc[d] += __shfl_down(acc[d], o);
  if (lane == 0)
#pragma unroll
    for (int d = 0; d < 8; d++) p.Ee[r * 8 + d] = acc[d];
}

// K5: gather32 (8 slots) + renorm (5000) | semb (79)
__global__ __launch_bounds__(256) void k5(Prm p) {
  __shared__ float El[1024];
  int b = blockIdx.x;
  int tid = threadIdx.x;
  if (b < 5000) {
    int w = tid >> 6;
    int lane = tid & 63;
    int slot = lane >> 3;
    int fi = lane & 7;
    int n = b * 4 + w;
    int s0 = p.start[n], cnt = p.ideg[n];
    float4 acc = {0.f, 0.f, 0.f, 0.f};
    for (int k = 0; k < cnt; k += 8) {
      int kk = k + slot;
      bool valid = kk < cnt;
      int src = valid ? p.csr[s0 + kk] : n;
      float wgt = valid ? p.dinv[src] : 0.0f;
      float4 v = ((const float4*)(p.h2raw + (size_t)src * 32))[fi];
      acc.x = fmaf(v.x, wgt, acc.x); acc.y = fmaf(v.y, wgt, acc.y);
      acc.z = fmaf(v.z, wgt, acc.z); acc.w = fmaf(v.w, wgt, acc.w);
    }
    acc.x += __shfl_xor(acc.x, 8);  acc.y += __shfl_xor(acc.y, 8);
    acc.z += __shfl_xor(acc.z, 8);  acc.w += __shfl_xor(acc.w, 8);
    acc.x += __shfl_xor(acc.x, 16); acc.y += __shfl_xor(acc.y, 16);
    acc.z += __shfl_xor(acc.z, 16); acc.w += __shfl_xor(acc.w, 16);
    acc.x += __shfl_xor(acc.x, 32); acc.y += __shfl_xor(acc.y, 32);
    acc.z += __shfl_xor(acc.z, 32); acc.w += __shfl_xor(acc.w, 32);
    float dn = p.dinv[n];
    float4 self = ((const float4*)(p.h2raw + (size_t)n * 32))[fi];
    float4 b2q = ((const float4*)p.b2)[fi];
    float4 h;
    h.x = fmaxf(fmaf(acc.x, dn, self.x * dn * dn) + b2q.x, 0.0f);
    h.y = fmaxf(fmaf(acc.y, dn, self.y * dn * dn) + b2q.y, 0.0f);
    h.z = fmaxf(fmaf(acc.z, dn, self.z * dn * dn) + b2q.z, 0.0f);
    h.w = fmaxf(fmaf(acc.w, dn, self.w * dn * dn) + b2q.w, 0.0f);
    float n2 = h.x * h.x + h.y * h.y + h.z * h.z + h.w * h.w;
    n2 += __shfl_xor(n2, 1); n2 += __shfl_xor(n2, 2); n2 += __shfl_xor(n2, 4);
    float nrm = sqrtf(n2);
    float sc = (nrm > 1.0f) ? 1.0f / (nrm + 1e-7f) : 1.0f;
    if (slot == 0) {
      float4 o; o.x = h.x * sc; o.y = h.y * sc; o.z = h.z * sc; o.w = h.w * sc;
      ((float4*)(p.g + (size_t)n * 32))[fi] = o;
    }
    return;
  }
  for (int u = tid; u < 256; u += 256)
    ((float4*)El)[u] = ((const float4*)p.Ee)[u];
  __syncthreads();
  int row = (b - 5000) * 256 + tid;
  if (row >= NN) return;
  const float4* xr4 = (const float4*)(p.x + (size_t)row * 128);
  float s[8] = {};
#pragma unroll 4
  for (int k4 = 0; k4 < 32; k4++) {
    float4 xv = xr4[k4];
    int kb = k4 * 4;
#pragma unroll
    for (int u = 0; u < 4; u++) {
      float xk = (u == 0) ? xv.x : (u == 1) ? xv.y : (u == 2) ? xv.z : xv.w;
      const float4* ep = (const float4*)&El[(kb + u) * 8];
      float4 e0 = ep[0], e1 = ep[1];
      s[0] = fmaf(xk, e0.x, s[0]); s[1] = fmaf(xk, e0.y, s[1]);
      s[2] = fmaf(xk, e0.z, s[2]); s[3] = fmaf(xk, e0.w, s[3]);
      s[4] = fmaf(xk, e1.x, s[4]); s[5] = fmaf(xk, e1.y, s[5]);
      s[6] = fmaf(xk, e1.z, s[6]); s[7] = fmaf(xk, e1.w, s[7]);
    }
  }
  float n2 = 0.0f;
#pragma unroll
  for (int d = 0; d < 8; d++) n2 += s[d] * s[d];
  float n = sqrtf(n2);
  float sc = (n > 1.0f) ? 1.0f / (n + 1e-7f) : 1.0f;
#pragma unroll
  for (int d = 0; d < 8; d++) p.semb[(size_t)row * 8 + d] = s[d] * sc;
}

// K6: query head (782)
__global__ __launch_bounds__(256) void k6(Prm p) {
  int q = blockIdx.x * 256 + threadIdx.x;
  if (q >= NQ) return;
  const int2 pr = ((const int2*)p.te)[q];
  int i0 = pr.x, i1 = pr.y;
  float feat[40];
  const float4* g0 = (const float4*)(p.g + (size_t)i0 * 32);
  const float4* g1 = (const float4*)(p.g + (size_t)i1 * 32);
#pragma unroll
  for (int u = 0; u < 8; u++) {
    float4 a = g0[u], b = g1[u];
    float d0 = a.x - b.x, d1 = a.y - b.y, d2 = a.z - b.z, d3 = a.w - b.w;
    feat[u * 4 + 0] = d0 * d0; feat[u * 4 + 1] = d1 * d1;
    feat[u * 4 + 2] = d2 * d2; feat[u * 4 + 3] = d3 * d3;
  }
  const float4* s0 = (const float4*)(p.semb + (size_t)i0 * 8);
  const float4* s1 = (const float4*)(p.semb + (size_t)i1 * 8);
#pragma unroll
  for (int u = 0; u < 2; u++) {
    float4 a = s0[u], b = s1[u];
    float d0 = a.x - b.x, d1 = a.y - b.y, d2 = a.z - b.z, d3 = a.w - b.w;
    feat[32 + u * 4 + 0] = 0.1f * d0 * d0; feat[32 + u * 4 + 1] = 0.1f * d1 * d1;
    feat[32 + u * 4 + 2] = 0.1f * d2 * d2; feat[32 + u * 4 + 3] = 0.1f * d3 * d3;
  }
  float acc[32];
#pragma unroll
  for (int c = 0; c < 32; c++) acc[c] = p.lin1b[c];
#pragma unroll
  for (int k = 0; k < 40; k++) {
    float f = feat[k];
#pragma unroll
    for (int c = 0; c < 32; c++) acc[c] = fmaf(f, p.lin1W[k * 32 + c], acc[c]);
  }
  float accv = p.linb[0];
#pragma unroll
  for (int c = 0; c < 32; c++) {
    float a = acc[c];
    a = (a > 0.0f) ? a : 0.2f * a;
    accv = fmaf(a, p.linW[c], accv);
  }
  float sq = fminf(fabsf(accv), 40.0f);
  p.out[q] = 1.0f / (1.0f + __expf(sq - 2.0f));
}

extern "C" void kernel_launch(void* const* d_in, const int* in_sizes, int n_in,
                              void* d_out, int out_size, void* d_ws, size_t ws_size,
                              hipStream_t stream) {
  Prm p;
  p.x     = (const float*)d_in[0];
  p.L0    = (const float*)d_in[1];
  p.L1    = (const float*)d_in[2];
  p.ei    = (const int*)d_in[3];
  p.te    = (const int*)d_in[4];
  p.W1    = (const float*)d_in[5];
  p.b1    = (const float*)d_in[6];
  p.W2    = (const float*)d_in[7];
  p.b2    = (const float*)d_in[8];
  p.wsim  = (const float*)d_in[9];
  p.embs  = (const float*)d_in[10];
  p.wod   = (const float*)d_in[11];
  p.wL0   = (const float*)d_in[12];
  p.wL1   = (const float*)d_in[13];
  p.lin1W = (const float*)d_in[14];
  p.lin1b = (const float*)d_in[15];
  p.linW  = (const float*)d_in[16];
  p.linb  = (const float*)d_in[17];
  p.out   = (float*)d_out;

  p.ideg   = (int*)d_ws;                    // 20,000
  p.start  = p.ideg + 20000;                // 20,000
  p.cursor = p.start + 20000;               // 20,000
  p.csr    = p.cursor + 20000;              // 320,000
  p.dinv   = (float*)(p.csr + 320000);      // 20,000
  p.h1raw  = p.dinv + 20000;                // 1,280,000
  p.h2raw  = p.h1raw + 1280000;             // 640,000
  p.g      = p.h2raw + 640000;              // 640,000
  p.L0r    = p.g + 640000;                  // 262,144
  p.L1r    = p.L0r + 262144;                // 262,144 (contiguous with L0r)
  p.T0     = p.L1r + 262144;                // 16,384
  p.T1     = p.T0 + 16384;                  // 16,384
  p.Bb     = p.T1 + 16384;                  // 16,384
  p.Ab2    = p.Bb + 16384;                  // 16,384
  p.Mm     = p.Ab2 + 16384;                 // 8,192
  p.Ee     = p.Mm + 8192;                   // 1,024
  p.semb   = p.Ee + 1024;                   // 160,000
  p.Cpart  = p.semb + 160000;               // 3,145,728 (4 slices x 3 x 512x512)

  hipMemsetAsync(p.ideg, 0, 20000 * sizeof(int), stream);
  k1a<<<800,  256, 0, stream>>>(p);
  k1b<<<1250, 256, 0, stream>>>(p);
  k1c<<<1250, 256, 0, stream>>>(p);
  k2<<<545,   256, 0, stream>>>(p);
  k3<<<2274,  256, 0, stream>>>(p);
  k4<<<5032,  256, 0, stream>>>(p);
  k5<<<5079,  256, 0, stream>>>(p);
  k6<<<782,   256, 0, stream>>>(p);
}

// Round 15
// 156.736 us; speedup vs baseline: 1.2925x; 1.1447x over previous
//
#include <hip/hip_runtime.h>
#include <math.h>

#define NE 320000
#define NN 20000
#define NQ 200000

struct Prm {
  const float *x, *L0, *L1;
  const int *ei, *te;
  const float *W1, *b1, *W2, *b2, *wsim, *embs, *wod, *wL0, *wL1, *lin1W, *lin1b, *linW, *linb;
  float *out;
  int *ideg, *start, *cursor, *csr;
  float *dinv, *h1raw, *h2raw, *g, *L0r, *L1r, *U, *V0, *V1, *Ab2, *Bb, *Mm, *Ee, *semb;
};

// ---- 512^3 f32 GEMM tile: C = A@B, 64x64 tile, 4x4 microtile (round-7 form) ----
__device__ __forceinline__ void gemm512_ab(char* smem, const float* __restrict__ A,
                                           const float* __restrict__ B,
                                           float* __restrict__ C, int bb) {
  float (*As)[68] = (float(*)[68])smem;
  float (*Bs)[68] = (float(*)[68])(smem + 16 * 68 * 4);
  int tid = threadIdx.x;
  int tx = tid & 15, ty = tid >> 4;
  int brow = (bb >> 3) * 64;
  int bcol = (bb & 7) * 64;
  float c[4][4] = {};
  for (int k0 = 0; k0 < 512; k0 += 16) {
#pragma unroll
    for (int t = 0; t < 4; t++) {
      int idx = tid * 4 + t;
      int r = idx >> 4, cc = idx & 15;
      As[cc][r] = A[(size_t)(brow + r) * 512 + k0 + cc];
      int r2 = idx >> 6, c2 = idx & 63;
      Bs[r2][c2] = B[(size_t)(k0 + r2) * 512 + bcol + c2];
    }
    __syncthreads();
#pragma unroll
    for (int k = 0; k < 16; k++) {
      float a0 = As[k][ty * 4 + 0], a1 = As[k][ty * 4 + 1];
      float a2 = As[k][ty * 4 + 2], a3 = As[k][ty * 4 + 3];
      float b0 = Bs[k][tx * 4 + 0], b1 = Bs[k][tx * 4 + 1];
      float b2 = Bs[k][tx * 4 + 2], b3 = Bs[k][tx * 4 + 3];
      c[0][0] = fmaf(a0, b0, c[0][0]); c[0][1] = fmaf(a0, b1, c[0][1]);
      c[0][2] = fmaf(a0, b2, c[0][2]); c[0][3] = fmaf(a0, b3, c[0][3]);
      c[1][0] = fmaf(a1, b0, c[1][0]); c[1][1] = fmaf(a1, b1, c[1][1]);
      c[1][2] = fmaf(a1, b2, c[1][2]); c[1][3] = fmaf(a1, b3, c[1][3]);
      c[2][0] = fmaf(a2, b0, c[2][0]); c[2][1] = fmaf(a2, b1, c[2][1]);
      c[2][2] = fmaf(a2, b2, c[2][2]); c[2][3] = fmaf(a2, b3, c[2][3]);
      c[3][0] = fmaf(a3, b0, c[3][0]); c[3][1] = fmaf(a3, b1, c[3][1]);
      c[3][2] = fmaf(a3, b2, c[3][2]); c[3][3] = fmaf(a3, b3, c[3][3]);
    }
    __syncthreads();
  }
#pragma unroll
  for (int i = 0; i < 4; i++)
#pragma unroll
    for (int j = 0; j < 4; j++)
      C[(size_t)(brow + ty * 4 + i) * 512 + bcol + tx * 4 + j] = c[i][j];
}

// ---- skinny GEMM, W staged in LDS in 8KB K-chunks: Y = X@W ----
template<int K, int N, int KC>
__device__ __forceinline__ void xw_chunk(char* smem, const float* __restrict__ X,
                                         const float* __restrict__ W,
                                         float* __restrict__ Y, int bb, int M) {
  constexpr int TPR = N / 4;
  constexpr int ROWS = 256 / TPR;
  float* Wl = (float*)smem;
  int r = bb * ROWS + threadIdx.x / TPR;
  int c4 = (threadIdx.x % TPR) * 4;
  float a0 = 0, a1 = 0, a2 = 0, a3 = 0;
#pragma unroll 1
  for (int k0 = 0; k0 < K; k0 += KC) {
    __syncthreads();
    for (int t = threadIdx.x; t < KC * N / 4; t += 256)
      ((float4*)Wl)[t] = ((const float4*)(W + k0 * N))[t];
    __syncthreads();
    if (r < M) {
      const float4* xr4 = (const float4*)(X + (size_t)r * K + k0);
#pragma unroll
      for (int k4 = 0; k4 < KC / 4; k4++) {
        float4 xv = xr4[k4];
        int kb = k4 * 4;
        { const float4 w = *(const float4*)&Wl[(kb + 0) * N + c4];
          a0 = fmaf(xv.x, w.x, a0); a1 = fmaf(xv.x, w.y, a1); a2 = fmaf(xv.x, w.z, a2); a3 = fmaf(xv.x, w.w, a3); }
        { const float4 w = *(const float4*)&Wl[(kb + 1) * N + c4];
          a0 = fmaf(xv.y, w.x, a0); a1 = fmaf(xv.y, w.y, a1); a2 = fmaf(xv.y, w.z, a2); a3 = fmaf(xv.y, w.w, a3); }
        { const float4 w = *(const float4*)&Wl[(kb + 2) * N + c4];
          a0 = fmaf(xv.z, w.x, a0); a1 = fmaf(xv.z, w.y, a1); a2 = fmaf(xv.z, w.z, a2); a3 = fmaf(xv.z, w.w, a3); }
        { const float4 w = *(const float4*)&Wl[(kb + 3) * N + c4];
          a0 = fmaf(xv.w, w.x, a0); a1 = fmaf(xv.w, w.y, a1); a2 = fmaf(xv.w, w.z, a2); a3 = fmaf(xv.w, w.w, a3); }
      }
    }
  }
  if (r < M) {
    float4 o; o.x = a0; o.y = a1; o.z = a2; o.w = a3;
    *(float4*)&Y[(size_t)r * N + c4] = o;
  }
}

// ---- Y(512x32) = X(512x512)@W(512x32), W streamed ----
__device__ __forceinline__ void sk512_body(const float* X, const float* W, float* Y, int b) {
  int r = b * 32 + threadIdx.x / 8;
  int c4 = (threadIdx.x % 8) * 4;
  const float4* xr4 = (const float4*)(X + (size_t)r * 512);
  float a0 = 0, a1 = 0, a2 = 0, a3 = 0;
#pragma unroll 2
  for (int k4 = 0; k4 < 128; k4++) {
    float4 xv = xr4[k4];
    int kb = k4 * 4;
    { const float4 w = *(const float4*)&W[(kb + 0) * 32 + c4];
      a0 = fmaf(xv.x, w.x, a0); a1 = fmaf(xv.x, w.y, a1); a2 = fmaf(xv.x, w.z, a2); a3 = fmaf(xv.x, w.w, a3); }
    { const float4 w = *(const float4*)&W[(kb + 1) * 32 + c4];
      a0 = fmaf(xv.y, w.x, a0); a1 = fmaf(xv.y, w.y, a1); a2 = fmaf(xv.y, w.z, a2); a3 = fmaf(xv.y, w.w, a3); }
    { const float4 w = *(const float4*)&W[(kb + 2) * 32 + c4];
      a0 = fmaf(xv.z, w.x, a0); a1 = fmaf(xv.z, w.y, a1); a2 = fmaf(xv.z, w.z, a2); a3 = fmaf(xv.z, w.w, a3); }
    { const float4 w = *(const float4*)&W[(kb + 3) * 32 + c4];
      a0 = fmaf(xv.w, w.x, a0); a1 = fmaf(xv.w, w.y, a1); a2 = fmaf(xv.w, w.z, a2); a3 = fmaf(xv.w, w.w, a3); }
  }
  float4 o; o.x = a0; o.y = a1; o.z = a2; o.w = a3;
  *(float4*)&Y[(size_t)r * 32 + c4] = o;
}

// ================= kernels (round-7 schedule) =================

// K1: L0r,L1r,U=wod@L0 (gemm512 x3, 192) | V0,V1 (32) | xw1 8KB-chunked (1250) | hist (1250)
__global__ __launch_bounds__(256) void k1(Prm p) {
  __shared__ __align__(16) char smem[8704];
  int b = blockIdx.x;
  if (b < 64)        gemm512_ab(smem, p.L0, p.L0, p.L0r, b);
  else if (b < 128)  gemm512_ab(smem, p.L1, p.L1, p.L1r, b - 64);
  else if (b < 192)  gemm512_ab(smem, p.wod, p.L0, p.U, b - 128);
  else if (b < 208)  sk512_body(p.L0, p.wL0, p.V0, b - 192);
  else if (b < 224)  sk512_body(p.L1, p.wL1, p.V1, b - 208);
  else if (b < 1474) xw_chunk<128, 64, 32>(smem, p.x, p.W1, p.h1raw, b - 224, NN);
  else {
    int e = (b - 1474) * 256 + threadIdx.x;
    if (e < NE) atomicAdd(&p.ideg[p.ei[NE + e]], 1);
  }
}

// K2: Ab2 = U@V0 (16) | Bb = L1@V1 (16) | scan (1)
__global__ __launch_bounds__(256) void k2(Prm p) {
  int b = blockIdx.x;
  if (b < 16) { sk512_body(p.U, p.V0, p.Ab2, b); return; }
  if (b < 32) { sk512_body(p.L1, p.V1, p.Bb, b - 16); return; }
  // exclusive scan over 20000 degrees: 256 thr x 80 contiguous ints
  __shared__ int wsum[4];
  int tid = threadIdx.x;
  int base = tid * 80;
  int4 c[20];
  int s = 0;
  if (base < NN) {
    const int4* ip = (const int4*)p.ideg + tid * 20;
#pragma unroll
    for (int i = 0; i < 20; i++) c[i] = ip[i];
#pragma unroll
    for (int i = 0; i < 20; i++) s += c[i].x + c[i].y + c[i].z + c[i].w;
  }
  int lane = tid & 63, wid = tid >> 6;
  int v = s;
#pragma unroll
  for (int o = 1; o < 64; o <<= 1) { int u = __shfl_up(v, o); if (lane >= o) v += u; }
  if (lane == 63) wsum[wid] = v;
  __syncthreads();
  int wbase = 0;
  for (int w = 0; w < wid; w++) wbase += wsum[w];
  int off = wbase + v - s;
  if (base < NN) {
#pragma unroll
    for (int i = 0; i < 20; i++) {
      int4 cc = c[i];
      int4 st;
      st.x = off; off += cc.x;
      st.y = off; off += cc.y;
      st.z = off; off += cc.z;
      st.w = off; off += cc.w;
      ((int4*)p.start)[tid * 20 + i] = st;
      ((int4*)p.cursor)[tid * 20 + i] = st;
      float4 dv;
      dv.x = rsqrtf((float)(cc.x + 1));
      dv.y = rsqrtf((float)(cc.y + 1));
      dv.z = rsqrtf((float)(cc.z + 1));
      dv.w = rsqrtf((float)(cc.w + 1));
      ((float4*)p.dinv)[tid * 20 + i] = dv;
    }
  }
}

// K3: softmaxM with fused rel_ (0..1023) | scatter (1024..2273)
__global__ __launch_bounds__(256) void k3(Prm p) {
  int b = blockIdx.x;
  int tid = threadIdx.x;
  if (b >= 1024) {
    int e = (b - 1024) * 256 + tid;
    if (e < NE) {
      int d = p.ei[NE + e];
      int pos = atomicAdd(&p.cursor[d], 1);
      p.csr[pos] = p.ei[e];
    }
    return;
  }
  int i = b;
  __shared__ float smax[4];
  __shared__ float sred[4][9];
  float urow[32];
  {
    const float4* up = (const float4*)((i < 512) ? (p.Ab2 + i * 32) : (p.Bb + (i - 512) * 32));
#pragma unroll
    for (int q = 0; q < 8; q++) {
      float4 u4 = up[q];
      urow[q * 4 + 0] = u4.x; urow[q * 4 + 1] = u4.y;
      urow[q * 4 + 2] = u4.z; urow[q * 4 + 3] = u4.w;
    }
  }
  float loc[4];
  float mymax = 0.0f;  // post-relu >= 0
#pragma unroll
  for (int tt = 0; tt < 4; tt++) {
    int j = tid + tt * 256;
    float v;
    if (i < 512) {
      if (j < 512) v = p.L0r[i * 512 + j];
      else {
        const float4* bj = (const float4*)(p.Bb + (j - 512) * 32);
        float acc = 0.0f;
#pragma unroll
        for (int q = 0; q < 8; q++) {
          float4 b4 = bj[q];
          acc = fmaf(urow[q * 4 + 0], b4.x, acc); acc = fmaf(urow[q * 4 + 1], b4.y, acc);
          acc = fmaf(urow[q * 4 + 2], b4.z, acc); acc = fmaf(urow[q * 4 + 3], b4.w, acc);
        }
        v = acc;
      }
    } else {
      int r = i - 512;
      if (j < 512) {
        const float4* aj = (const float4*)(p.Ab2 + j * 32);
        float acc = 0.0f;
#pragma unroll
        for (int q = 0; q < 8; q++) {
          float4 a4 = aj[q];
          acc = fmaf(urow[q * 4 + 0], a4.x, acc); acc = fmaf(urow[q * 4 + 1], a4.y, acc);
          acc = fmaf(urow[q * 4 + 2], a4.z, acc); acc = fmaf(urow[q * 4 + 3], a4.w, acc);
        }
        v = acc;
      } else v = p.L1r[r * 512 + (j - 512)];
    }
    v = fmaxf(v, 0.0f);
    loc[tt] = v;
    mymax = fmaxf(mymax, v);
  }
#pragma unroll
  for (int o = 32; o > 0; o >>= 1) mymax = fmaxf(mymax, __shfl_down(mymax, o));
  int wid = tid >> 6, lane = tid & 63;
  if (lane == 0) smax[wid] = mymax;
  __syncthreads();
  float m = fmaxf(fmaxf(smax[0], smax[1]), fmaxf(smax[2], smax[3]));

  float z = 0.0f, pm[8] = {};
#pragma unroll
  for (int tt = 0; tt < 4; tt++) {
    int j = tid + tt * 256;
    float e = __expf(loc[tt] - m);
    z += e;
    const float* wr = p.wsim + j * 8;
#pragma unroll
    for (int d = 0; d < 8; d++) pm[d] = fmaf(e, wr[d], pm[d]);
  }
#pragma unroll
  for (int o = 32; o > 0; o >>= 1) {
    z += __shfl_down(z, o);
#pragma unroll
    for (int d = 0; d < 8; d++) pm[d] += __shfl_down(pm[d], o);
  }
  if (lane == 0) {
    sred[wid][0] = z;
#pragma unroll
    for (int d = 0; d < 8; d++) sred[wid][1 + d] = pm[d];
  }
  __syncthreads();
  if (tid < 8) {
    float zt = sred[0][0] + sred[1][0] + sred[2][0] + sred[3][0];
    float pt = sred[0][1 + tid] + sred[1][1 + tid] + sred[2][1 + tid] + sred[3][1 + tid];
    p.Mm[i * 8 + tid] = pt / zt;
  }
}

// K4: gather64 (4 slots) + fused xw2 (5000) | E (32)
__global__ __launch_bounds__(256) void k4(Prm p) {
  __shared__ float W2l[64 * 32];
  __shared__ float h1l[4][64];
  int b = blockIdx.x;
  int tid = threadIdx.x;
  if (b < 5000) {
    for (int u = tid; u < 512; u += 256)
      ((float4*)W2l)[u] = ((const float4*)p.W2)[u];
    __syncthreads();
    int w = tid >> 6;
    int lane = tid & 63;
    int slot = lane >> 4;
    int fi = lane & 15;
    int n = b * 4 + w;
    int s0 = p.start[n], cnt = p.ideg[n];
    float4 acc = {0.f, 0.f, 0.f, 0.f};
    for (int k = 0; k < cnt; k += 4) {
      int kk = k + slot;
      bool valid = kk < cnt;
      int src = valid ? p.csr[s0 + kk] : n;
      float wgt = valid ? p.dinv[src] : 0.0f;
      float4 v = ((const float4*)(p.h1raw + (size_t)src * 64))[fi];
      acc.x = fmaf(v.x, wgt, acc.x); acc.y = fmaf(v.y, wgt, acc.y);
      acc.z = fmaf(v.z, wgt, acc.z); acc.w = fmaf(v.w, wgt, acc.w);
    }
    acc.x += __shfl_xor(acc.x, 16); acc.y += __shfl_xor(acc.y, 16);
    acc.z += __shfl_xor(acc.z, 16); acc.w += __shfl_xor(acc.w, 16);
    acc.x += __shfl_xor(acc.x, 32); acc.y += __shfl_xor(acc.y, 32);
    acc.z += __shfl_xor(acc.z, 32); acc.w += __shfl_xor(acc.w, 32);
    float dn = p.dinv[n];
    float4 self = ((const float4*)(p.h1raw + (size_t)n * 64))[fi];
    float4 b1q = ((const float4*)p.b1)[fi];
    float4 h;
    h.x = fmaxf(fmaf(acc.x, dn, self.x * dn * dn) + b1q.x, 0.0f);
    h.y = fmaxf(fmaf(acc.y, dn, self.y * dn * dn) + b1q.y, 0.0f);
    h.z = fmaxf(fmaf(acc.z, dn, self.z * dn * dn) + b1q.z, 0.0f);
    h.w = fmaxf(fmaf(acc.w, dn, self.w * dn * dn) + b1q.w, 0.0f);
    if (slot == 0) ((float4*)h1l[w])[fi] = h;
    __syncthreads();
    int c = lane & 31, half = lane >> 5;
    float s = 0.0f;
    const float* hr = h1l[w];
#pragma unroll
    for (int kk2 = 0; kk2 < 32; kk2++) {
      int k = half * 32 + kk2;
      s = fmaf(hr[k], W2l[k * 32 + c], s);
    }
    s += __shfl_xor(s, 32);
    if (half == 0) p.h2raw[(size_t)n * 32 + c] = s;
    return;
  }
  int lane = tid & 63;
  int r = (b - 5000) * 4 + (tid >> 6);
  const float* er = p.embs + (size_t)r * 1024;
  float acc[8] = {};
  for (int it = 0; it < 16; it++) {
    int k = lane + it * 64;
    float e = er[k];
    const float4* mp = (const float4*)&p.Mm[k * 8];
    float4 m0 = mp[0], m1 = mp[1];
    acc[0] = fmaf(e, m0.x, acc[0]); acc[1] = fmaf(e, m0.y, acc[1]);
    acc[2] = fmaf(e, m0.z, acc[2]); acc[3] = fmaf(e, m0.w, acc[3]);
    acc[4] = fmaf(e, m1.x, acc[4]); acc[5] = fmaf(e, m1.y, acc[5]);
    acc[6] = fmaf(e, m1.z, acc[6]); acc[7] = fmaf(e, m1.w, acc[7]);
  }
#pragma unroll
  for (int o = 32; o > 0; o >>= 1)
#pragma unroll
    for (int d = 0; d < 8; d++) acc[d] += __shfl_down(acc[d], o);
  if (lane == 0)
#pragma unroll
    for (int d = 0; d < 8; d++) p.Ee[r * 8 + d] = acc[d];
}

// K5: gather32 (8 slots) + renorm (5000) | semb (79)
__global__ __launch_bounds__(256) void k5(Prm p) {
  __shared__ float El[1024];
  int b = blockIdx.x;
  int tid = threadIdx.x;
  if (b < 5000) {
    int w = tid >> 6;
    int lane = tid & 63;
    int slot = lane >> 3;
    int fi = lane & 7;
    int n = b * 4 + w;
    int s0 = p.start[n], cnt = p.ideg[n];
    float4 acc = {0.f, 0.f, 0.f, 0.f};
    for (int k = 0; k < cnt; k += 8) {
      int kk = k + slot;
      bool valid = kk < cnt;
      int src = valid ? p.csr[s0 + kk] : n;
      float wgt = valid ? p.dinv[src] : 0.0f;
      float4 v = ((const float4*)(p.h2raw + (size_t)src * 32))[fi];
      acc.x = fmaf(v.x, wgt, acc.x); acc.y = fmaf(v.y, wgt, acc.y);
      acc.z = fmaf(v.z, wgt, acc.z); acc.w = fmaf(v.w, wgt, acc.w);
    }
    acc.x += __shfl_xor(acc.x, 8);  acc.y += __shfl_xor(acc.y, 8);
    acc.z += __shfl_xor(acc.z, 8);  acc.w += __shfl_xor(acc.w, 8);
    acc.x += __shfl_xor(acc.x, 16); acc.y += __shfl_xor(acc.y, 16);
    acc.z += __shfl_xor(acc.z, 16); acc.w += __shfl_xor(acc.w, 16);
    acc.x += __shfl_xor(acc.x, 32); acc.y += __shfl_xor(acc.y, 32);
    acc.z += __shfl_xor(acc.z, 32); acc.w += __shfl_xor(acc.w, 32);
    float dn = p.dinv[n];
    float4 self = ((const float4*)(p.h2raw + (size_t)n * 32))[fi];
    float4 b2q = ((const float4*)p.b2)[fi];
    float4 h;
    h.x = fmaxf(fmaf(acc.x, dn, self.x * dn * dn) + b2q.x, 0.0f);
    h.y = fmaxf(fmaf(acc.y, dn, self.y * dn * dn) + b2q.y, 0.0f);
    h.z = fmaxf(fmaf(acc.z, dn, self.z * dn * dn) + b2q.z, 0.0f);
    h.w = fmaxf(fmaf(acc.w, dn, self.w * dn * dn) + b2q.w, 0.0f);
    float n2 = h.x * h.x + h.y * h.y + h.z * h.z + h.w * h.w;
    n2 += __shfl_xor(n2, 1); n2 += __shfl_xor(n2, 2); n2 += __shfl_xor(n2, 4);
    float nrm = sqrtf(n2);
    float sc = (nrm > 1.0f) ? 1.0f / (nrm + 1e-7f) : 1.0f;
    if (slot == 0) {
      float4 o; o.x = h.x * sc; o.y = h.y * sc; o.z = h.z * sc; o.w = h.w * sc;
      ((float4*)(p.g + (size_t)n * 32))[fi] = o;
    }
    return;
  }
  for (int u = tid; u < 256; u += 256)
    ((float4*)El)[u] = ((const float4*)p.Ee)[u];
  __syncthreads();
  int row = (b - 5000) * 256 + tid;
  if (row >= NN) return;
  const float4* xr4 = (const float4*)(p.x + (size_t)row * 128);
  float s[8] = {};
#pragma unroll 4
  for (int k4 = 0; k4 < 32; k4++) {
    float4 xv = xr4[k4];
    int kb = k4 * 4;
#pragma unroll
    for (int u = 0; u < 4; u++) {
      float xk = (u == 0) ? xv.x : (u == 1) ? xv.y : (u == 2) ? xv.z : xv.w;
      const float4* ep = (const float4*)&El[(kb + u) * 8];
      float4 e0 = ep[0], e1 = ep[1];
      s[0] = fmaf(xk, e0.x, s[0]); s[1] = fmaf(xk, e0.y, s[1]);
      s[2] = fmaf(xk, e0.z, s[2]); s[3] = fmaf(xk, e0.w, s[3]);
      s[4] = fmaf(xk, e1.x, s[4]); s[5] = fmaf(xk, e1.y, s[5]);
      s[6] = fmaf(xk, e1.z, s[6]); s[7] = fmaf(xk, e1.w, s[7]);
    }
  }
  float n2 = 0.0f;
#pragma unroll
  for (int d = 0; d < 8; d++) n2 += s[d] * s[d];
  float n = sqrtf(n2);
  float sc = (n > 1.0f) ? 1.0f / (n + 1e-7f) : 1.0f;
#pragma unroll
  for (int d = 0; d < 8; d++) p.semb[(size_t)row * 8 + d] = s[d] * sc;
}

// K6: query head (782)
__global__ __launch_bounds__(256) void k6(Prm p) {
  int q = blockIdx.x * 256 + threadIdx.x;
  if (q >= NQ) return;
  const int2 pr = ((const int2*)p.te)[q];
  int i0 = pr.x, i1 = pr.y;
  float feat[40];
  const float4* g0 = (const float4*)(p.g + (size_t)i0 * 32);
  const float4* g1 = (const float4*)(p.g + (size_t)i1 * 32);
#pragma unroll
  for (int u = 0; u < 8; u++) {
    float4 a = g0[u], b = g1[u];
    float d0 = a.x - b.x, d1 = a.y - b.y, d2 = a.z - b.z, d3 = a.w - b.w;
    feat[u * 4 + 0] = d0 * d0; feat[u * 4 + 1] = d1 * d1;
    feat[u * 4 + 2] = d2 * d2; feat[u * 4 + 3] = d3 * d3;
  }
  const float4* s0 = (const float4*)(p.semb + (size_t)i0 * 8);
  const float4* s1 = (const float4*)(p.semb + (size_t)i1 * 8);
#pragma unroll
  for (int u = 0; u < 2; u++) {
    float4 a = s0[u], b = s1[u];
    float d0 = a.x - b.x, d1 = a.y - b.y, d2 = a.z - b.z, d3 = a.w - b.w;
    feat[32 + u * 4 + 0] = 0.1f * d0 * d0; feat[32 + u * 4 + 1] = 0.1f * d1 * d1;
    feat[32 + u * 4 + 2] = 0.1f * d2 * d2; feat[32 + u * 4 + 3] = 0.1f * d3 * d3;
  }
  float acc[32];
#pragma unroll
  for (int c = 0; c < 32; c++) acc[c] = p.lin1b[c];
#pragma unroll
  for (int k = 0; k < 40; k++) {
    float f = feat[k];
#pragma unroll
    for (int c = 0; c < 32; c++) acc[c] = fmaf(f, p.lin1W[k * 32 + c], acc[c]);
  }
  float accv = p.linb[0];
#pragma unroll
  for (int c = 0; c < 32; c++) {
    float a = acc[c];
    a = (a > 0.0f) ? a : 0.2f * a;
    accv = fmaf(a, p.linW[c], accv);
  }
  float sq = fminf(fabsf(accv), 40.0f);
  p.out[q] = 1.0f / (1.0f + __expf(sq - 2.0f));
}

extern "C" void kernel_launch(void* const* d_in, const int* in_sizes, int n_in,
                              void* d_out, int out_size, void* d_ws, size_t ws_size,
                              hipStream_t stream) {
  Prm p;
  p.x     = (const float*)d_in[0];
  p.L0    = (const float*)d_in[1];
  p.L1    = (const float*)d_in[2];
  p.ei    = (const int*)d_in[3];
  p.te    = (const int*)d_in[4];
  p.W1    = (const float*)d_in[5];
  p.b1    = (const float*)d_in[6];
  p.W2    = (const float*)d_in[7];
  p.b2    = (const float*)d_in[8];
  p.wsim  = (const float*)d_in[9];
  p.embs  = (const float*)d_in[10];
  p.wod   = (const float*)d_in[11];
  p.wL0   = (const float*)d_in[12];
  p.wL1   = (const float*)d_in[13];
  p.lin1W = (const float*)d_in[14];
  p.lin1b = (const float*)d_in[15];
  p.linW  = (const float*)d_in[16];
  p.linb  = (const float*)d_in[17];
  p.out   = (float*)d_out;

  p.ideg   = (int*)d_ws;                    // 20,000
  p.start  = p.ideg + 20000;                // 20,000
  p.cursor = p.start + 20000;               // 20,000
  p.csr    = p.cursor + 20000;              // 320,000
  p.dinv   = (float*)(p.csr + 320000);      // 20,000
  p.h1raw  = p.dinv + 20000;                // 1,280,000
  p.h2raw  = p.h1raw + 1280000;             // 640,000
  p.g      = p.h2raw + 640000;              // 640,000
  p.L0r    = p.g + 640000;                  // 262,144
  p.L1r    = p.L0r + 262144;                // 262,144
  p.U      = p.L1r + 262144;                // 262,144
  p.V0     = p.U + 262144;                  // 16,384
  p.V1     = p.V0 + 16384;                  // 16,384
  p.Ab2    = p.V1 + 16384;                  // 16,384
  p.Bb     = p.Ab2 + 16384;                 // 16,384
  p.Mm     = p.Bb + 16384;                  // 8,192
  p.Ee     = p.Mm + 8192;                   // 1,024
  p.semb   = p.Ee + 1024;                   // 160,000

  hipMemsetAsync(p.ideg, 0, 20000 * sizeof(int), stream);
  k1<<<2724, 256, 0, stream>>>(p);
  k2<<<33,   256, 0, stream>>>(p);
  k3<<<2274, 256, 0, stream>>>(p);
  k4<<<5032, 256, 0, stream>>>(p);
  k5<<<5079, 256, 0, stream>>>(p);
  k6<<<782,  256, 0, stream>>>(p);
}